// Round 1
// baseline (2656.948 us; speedup 1.0000x reference)
//
#include <hip/hip_runtime.h>
#include <hip/hip_bf16.h>

// Problem constants: B=2, S=2048, D=1024, H=16, HD=64, E=4, K=2, HID=4096, T=4096
#define T_TOK 4096
#define DIM   1024
#define NHEAD 16
#define HDIM  64
#define SEQ   2048
#define NEXP  4
#define HIDD  4096

typedef short bf16x8 __attribute__((ext_vector_type(8)));
typedef float f32x4  __attribute__((ext_vector_type(4)));

enum { GF_GELU = 1, GF_RESID = 2, GF_SCALE = 4, GF_ACCUM = 8 };

__device__ inline unsigned short f2bf(float f) {
  union { float f; unsigned u; } v; v.f = f;
  unsigned r = v.u + 0x7FFFu + ((v.u >> 16) & 1u);
  return (unsigned short)(r >> 16);
}
__device__ inline int pack2(float a, float b) {
  return (int)((unsigned)f2bf(a) | ((unsigned)f2bf(b) << 16));
}
__device__ inline float gelu_f(float x) {
  const float c = 0.7978845608028654f;
  float t = tanhf(c * (x + 0.044715f * x * x * x));
  return 0.5f * x * (1.0f + t);
}

// ---------------------------------------------------------------------------
// Generic C = A @ W^T + bias (+epilogue).  A: MxK f32, W: NxK f32, C: MxN f32.
// BM=BN=64, BK=32, 256 threads (4 waves, each 32x32 = 2x2 MFMA 16x16x32 tiles)
// ---------------------------------------------------------------------------
__global__ __launch_bounds__(256) void gemm_kernel(
    const float* __restrict__ A, const float* __restrict__ W,
    const float* __restrict__ bias, const float* __restrict__ resid,
    const float* __restrict__ scale, float* __restrict__ C,
    int M, int N, int Kd, int flags)
{
  __shared__ __align__(16) short As[64][40];   // bf16 bits, row stride 80B
  __shared__ __align__(16) short Bs[64][40];

  const int tid  = threadIdx.x;
  const int bm   = blockIdx.y, bn = blockIdx.x;
  const int lrow = tid >> 2;            // 0..63
  const int lcg  = (tid & 3) << 3;      // 0,8,16,24 (K offset, elems)
  const float* Ap = A + (size_t)(bm * 64 + lrow) * Kd + lcg;
  const float* Wp = W + (size_t)(bn * 64 + lrow) * Kd + lcg;

  const int lane = tid & 63;
  const int wave = tid >> 6;
  const int wr   = (wave >> 1) << 5;    // wave m offset (0/32)
  const int wc   = (wave & 1) << 5;     // wave n offset (0/32)
  const int fr   = lane & 15;           // fragment row (A) / col (B,D)
  const int fq   = (lane >> 4) << 3;    // fragment k offset (elems)
  const int quad = lane >> 4;

  f32x4 acc[2][2] = {};

  for (int k0 = 0; k0 < Kd; k0 += 32) {
    float4 a0 = *(const float4*)(Ap + k0);
    float4 a1 = *(const float4*)(Ap + k0 + 4);
    float4 w0 = *(const float4*)(Wp + k0);
    float4 w1 = *(const float4*)(Wp + k0 + 4);
    __syncthreads();  // previous tile fully consumed
    int4 av = make_int4(pack2(a0.x, a0.y), pack2(a0.z, a0.w),
                        pack2(a1.x, a1.y), pack2(a1.z, a1.w));
    int4 wv = make_int4(pack2(w0.x, w0.y), pack2(w0.z, w0.w),
                        pack2(w1.x, w1.y), pack2(w1.z, w1.w));
    *(int4*)&As[lrow][lcg] = av;
    *(int4*)&Bs[lrow][lcg] = wv;
    __syncthreads();  // tile visible
    bf16x8 af0 = *(const bf16x8*)&As[wr + fr][fq];
    bf16x8 af1 = *(const bf16x8*)&As[wr + 16 + fr][fq];
    bf16x8 bf0 = *(const bf16x8*)&Bs[wc + fr][fq];
    bf16x8 bf1 = *(const bf16x8*)&Bs[wc + 16 + fr][fq];
    acc[0][0] = __builtin_amdgcn_mfma_f32_16x16x32_bf16(af0, bf0, acc[0][0], 0, 0, 0);
    acc[0][1] = __builtin_amdgcn_mfma_f32_16x16x32_bf16(af0, bf1, acc[0][1], 0, 0, 0);
    acc[1][0] = __builtin_amdgcn_mfma_f32_16x16x32_bf16(af1, bf0, acc[1][0], 0, 0, 0);
    acc[1][1] = __builtin_amdgcn_mfma_f32_16x16x32_bf16(af1, bf1, acc[1][1], 0, 0, 0);
  }

  for (int mt = 0; mt < 2; ++mt)
    for (int nt = 0; nt < 2; ++nt)
      for (int r = 0; r < 4; ++r) {
        int row = bm * 64 + wr + mt * 16 + quad * 4 + r;
        int col = bn * 64 + wc + nt * 16 + fr;
        float v = acc[mt][nt][r];
        if (bias) v += bias[col];
        if (flags & GF_GELU) v = gelu_f(v);
        if (flags & GF_RESID) v += resid[(size_t)row * N + col];
        if (flags & GF_SCALE) v *= scale[row];
        size_t idx = (size_t)row * N + col;
        if (flags & GF_ACCUM) C[idx] += v; else C[idx] = v;
      }
}

// ---------------------------------------------------------------------------
// fp32 flash attention, causal.  Grid (S/64, B*H), 256 threads.
// Each thread: 4x4 micro-tile of the 64x64 score tile. P aliases Ks.
// ---------------------------------------------------------------------------
__global__ __launch_bounds__(256) void attn_kernel(
    const float* __restrict__ qkv, float* __restrict__ o)
{
  __shared__ __align__(16) float Qs[64][68];
  __shared__ __align__(16) float Ks[64][68];   // also holds P after S-compute
  __shared__ __align__(16) float Vs[64][68];

  const int tid = threadIdx.x;
  const int qb  = blockIdx.x;
  const int bh  = blockIdx.y;
  const int b   = bh >> 4, h = bh & 15;
  const int q0  = qb << 6;

  const int ldr = tid >> 2;             // load row 0..63
  const int ldc = (tid & 3) << 4;       // load col base (16 floats)
  const float* qp = qkv + ((size_t)(b * SEQ + q0 + ldr)) * 3072 + h * 64 + ldc;
  for (int i = 0; i < 16; i += 4)
    *(float4*)&Qs[ldr][ldc + i] = *(const float4*)(qp + i);

  const int r4 = (tid >> 4) << 2;       // thread rows r4..r4+3
  const int c4 = (tid & 15) << 2;       // thread cols c4..c4+3

  float Oa[4][4] = {};
  float mr[4] = {-1e30f, -1e30f, -1e30f, -1e30f};
  float lsum[4] = {0.f, 0.f, 0.f, 0.f};

  for (int kt = 0; kt <= qb; ++kt) {
    const float* kp = qkv + ((size_t)(b * SEQ + (kt << 6) + ldr)) * 3072 + 1024 + h * 64 + ldc;
    const float* vp = kp + 1024;
    float4 kreg[4], vreg[4];
    for (int i = 0; i < 4; ++i) {
      kreg[i] = *(const float4*)(kp + i * 4);
      vreg[i] = *(const float4*)(vp + i * 4);
    }
    __syncthreads();  // prev PV done (and Qs visible on first iter)
    for (int i = 0; i < 4; ++i) {
      *(float4*)&Ks[ldr][ldc + i * 4] = kreg[i];
      *(float4*)&Vs[ldr][ldc + i * 4] = vreg[i];
    }
    __syncthreads();  // K/V visible

    float s[4][4] = {};
    for (int d = 0; d < 64; d += 4) {
      float4 qv[4], kv[4];
      for (int i = 0; i < 4; ++i) qv[i] = *(const float4*)&Qs[r4 + i][d];
      for (int j = 0; j < 4; ++j) kv[j] = *(const float4*)&Ks[c4 + j][d];
      for (int i = 0; i < 4; ++i)
        for (int j = 0; j < 4; ++j)
          s[i][j] += qv[i].x * kv[j].x + qv[i].y * kv[j].y +
                     qv[i].z * kv[j].z + qv[i].w * kv[j].w;
    }
    const bool diag = (kt == qb);
    float cm[4];
    for (int i = 0; i < 4; ++i) {
      for (int j = 0; j < 4; ++j) {
        float v = s[i][j] * 0.125f;
        if (diag && (c4 + j) > (r4 + i)) v = -1e9f;
        s[i][j] = v;
      }
      cm[i] = fmaxf(fmaxf(s[i][0], s[i][1]), fmaxf(s[i][2], s[i][3]));
    }
    for (int off = 1; off < 16; off <<= 1)
      for (int i = 0; i < 4; ++i) cm[i] = fmaxf(cm[i], __shfl_xor(cm[i], off, 64));
    float al[4];
    for (int i = 0; i < 4; ++i) {
      float nm = fmaxf(mr[i], cm[i]);
      al[i] = __expf(mr[i] - nm);
      mr[i] = nm;
    }
    float ps[4];
    for (int i = 0; i < 4; ++i) {
      float a = 0.f;
      for (int j = 0; j < 4; ++j) { float p = __expf(s[i][j] - mr[i]); s[i][j] = p; a += p; }
      ps[i] = a;
    }
    for (int off = 1; off < 16; off <<= 1)
      for (int i = 0; i < 4; ++i) ps[i] += __shfl_xor(ps[i], off, 64);
    for (int i = 0; i < 4; ++i) {
      lsum[i] = lsum[i] * al[i] + ps[i];
      for (int j = 0; j < 4; ++j) Oa[i][j] *= al[i];
    }
    __syncthreads();  // all S reads of Ks done
    for (int i = 0; i < 4; ++i)
      *(float4*)&Ks[r4 + i][c4] = make_float4(s[i][0], s[i][1], s[i][2], s[i][3]);
    __syncthreads();  // P visible
    for (int k = 0; k < 64; ++k) {
      float4 vv = *(const float4*)&Vs[k][c4];
      for (int i = 0; i < 4; ++i) {
        float p = Ks[r4 + i][k];
        Oa[i][0] += p * vv.x; Oa[i][1] += p * vv.y;
        Oa[i][2] += p * vv.z; Oa[i][3] += p * vv.w;
      }
    }
  }
  float* op = o + ((size_t)(b * SEQ + q0)) * DIM + h * 64;
  for (int i = 0; i < 4; ++i) {
    float inv = 1.0f / lsum[i];
    float4 o4 = make_float4(Oa[i][0] * inv, Oa[i][1] * inv, Oa[i][2] * inv, Oa[i][3] * inv);
    *(float4*)(op + (size_t)(r4 + i) * DIM + c4) = o4;
  }
}

// ---------------------------------------------------------------------------
__global__ __launch_bounds__(256) void ln_kernel(
    const float* __restrict__ x, const float* __restrict__ g,
    const float* __restrict__ b, float* __restrict__ out)
{
  const int t = blockIdx.x, tid = threadIdx.x;
  const float* row = x + (size_t)t * DIM;
  float4 v = *(const float4*)(row + tid * 4);
  float s  = v.x + v.y + v.z + v.w;
  float s2 = v.x * v.x + v.y * v.y + v.z * v.z + v.w * v.w;
  for (int off = 1; off < 64; off <<= 1) {
    s  += __shfl_xor(s, off, 64);
    s2 += __shfl_xor(s2, off, 64);
  }
  __shared__ float red[8];
  const int wave = tid >> 6, lane = tid & 63;
  if (lane == 0) { red[wave] = s; red[4 + wave] = s2; }
  __syncthreads();
  float S  = red[0] + red[1] + red[2] + red[3];
  float S2 = red[4] + red[5] + red[6] + red[7];
  float mean = S * (1.0f / DIM);
  float var  = S2 * (1.0f / DIM) - mean * mean;
  float rstd = rsqrtf(var + 1e-5f);
  float4 gv = *(const float4*)(g + tid * 4);
  float4 bv = *(const float4*)(b + tid * 4);
  float4 o4;
  o4.x = (v.x - mean) * rstd * gv.x + bv.x;
  o4.y = (v.y - mean) * rstd * gv.y + bv.y;
  o4.z = (v.z - mean) * rstd * gv.z + bv.z;
  o4.w = (v.w - mean) * rstd * gv.w + bv.w;
  *(float4*)(out + (size_t)t * DIM + tid * 4) = o4;
}

// ---------------------------------------------------------------------------
__global__ __launch_bounds__(128) void router_kernel(
    const float* __restrict__ h2, const float* __restrict__ Wg,
    float* __restrict__ stab, float* __restrict__ pi_sum, float* __restrict__ fi_sum)
{
  const int t = blockIdx.x, tid = threadIdx.x;
  __shared__ float sm[4][128];
  float p0 = 0, p1 = 0, p2 = 0, p3 = 0;
  const float* hrow = h2 + (size_t)t * DIM;
  for (int i = tid; i < DIM; i += 128) {
    float hv = hrow[i];
    p0 += hv * Wg[i];
    p1 += hv * Wg[DIM + i];
    p2 += hv * Wg[2 * DIM + i];
    p3 += hv * Wg[3 * DIM + i];
  }
  sm[0][tid] = p0; sm[1][tid] = p1; sm[2][tid] = p2; sm[3][tid] = p3;
  __syncthreads();
  for (int s = 64; s > 0; s >>= 1) {
    if (tid < s)
      for (int e = 0; e < 4; ++e) sm[e][tid] += sm[e][tid + s];
    __syncthreads();
  }
  if (tid == 0) {
    float l[4] = { sm[0][0], sm[1][0], sm[2][0], sm[3][0] };
    float m = fmaxf(fmaxf(l[0], l[1]), fmaxf(l[2], l[3]));
    float pr[4]; float sum = 0.f;
    for (int e = 0; e < 4; ++e) { pr[e] = __expf(l[e] - m); sum += pr[e]; }
    for (int e = 0; e < 4; ++e) pr[e] /= sum;
    int i0 = 0;
    for (int e = 1; e < 4; ++e) if (pr[e] > pr[i0]) i0 = e;
    int i1 = -1;
    for (int e = 0; e < 4; ++e) if (e != i0 && (i1 < 0 || pr[e] > pr[i1])) i1 = e;
    float wsum = pr[i0] + pr[i1];
    for (int e = 0; e < 4; ++e)
      stab[(size_t)e * T_TOK + t] = (e == i0) ? pr[i0] / wsum : (e == i1) ? pr[i1] / wsum : 0.f;
    for (int e = 0; e < 4; ++e) atomicAdd(&pi_sum[e], pr[e]);
    atomicAdd(&fi_sum[i0], 1.0f);
    atomicAdd(&fi_sum[i1], 1.0f);
  }
}

__global__ void zero8_kernel(float* p) { if (threadIdx.x < 8) p[threadIdx.x] = 0.f; }

__global__ void aux_kernel(const float* __restrict__ pi_sum,
                           const float* __restrict__ fi_sum, float* __restrict__ out)
{
  float s = 0.f;
  for (int e = 0; e < 4; ++e) s += fi_sum[e] * pi_sum[e];
  // aux = ALPHA * E * sum_e (fi_sum/(T*K)) * (Pi_sum/T)
  out[0] = 0.01f * 4.0f * s / (2.0f * (float)T_TOK * (float)T_TOK);
}

__global__ __launch_bounds__(256) void add_kernel(
    const float* __restrict__ a, const float* __restrict__ b,
    float* __restrict__ out, int n)
{
  int i = blockIdx.x * 256 + threadIdx.x;
  if (i < n) out[i] = a[i] + b[i];
}

// ---------------------------------------------------------------------------
extern "C" void kernel_launch(void* const* d_in, const int* in_sizes, int n_in,
                              void* d_out, int out_size, void* d_ws, size_t ws_size,
                              hipStream_t stream)
{
  const float* x      = (const float*)d_in[0];
  const float* ln1_g  = (const float*)d_in[1];
  const float* ln1_b  = (const float*)d_in[2];
  const float* Wqkv   = (const float*)d_in[3];
  const float* bqkv   = (const float*)d_in[4];
  const float* Wo     = (const float*)d_in[5];
  const float* bo     = (const float*)d_in[6];
  const float* ln2_g  = (const float*)d_in[7];
  const float* ln2_b  = (const float*)d_in[8];
  const float* Wg     = (const float*)d_in[9];
  const float* We_up  = (const float*)d_in[10];
  const float* be_up  = (const float*)d_in[11];
  const float* We_dn  = (const float*)d_in[12];
  const float* be_dn  = (const float*)d_in[13];
  const float* Ws_up  = (const float*)d_in[14];
  const float* bs_up  = (const float*)d_in[15];
  const float* Ws_dn  = (const float*)d_in[16];
  const float* bs_dn  = (const float*)d_in[17];

  float* out = (float*)d_out;
  float* ws  = (float*)d_ws;
  const size_t TD = (size_t)T_TOK * DIM;   // 4,194,304

  float* h    = ws;               // T x D     (h, then h2)
  float* qkv  = ws + TD;          // T x 3D
  float* o    = ws + 4 * TD;      // T x D
  float* x1   = ws + 5 * TD;      // T x D
  float* y    = ws + 6 * TD;      // T x D
  float* up   = ws + TD;          // T x HID   (overlaps dead qkv+o)
  float* stab = ws + 7 * TD;      // E x T routing scales
  float* pifi = stab + (size_t)NEXP * T_TOK;  // 4 Pi sums + 4 fi sums

  // 1) h = LN1(x)
  ln_kernel<<<T_TOK, 256, 0, stream>>>(x, ln1_g, ln1_b, h);
  // 2) qkv = h @ Wqkv^T + bqkv
  gemm_kernel<<<dim3(3072 / 64, T_TOK / 64), 256, 0, stream>>>(
      h, Wqkv, bqkv, nullptr, nullptr, qkv, T_TOK, 3072, DIM, 0);
  // 3) o = causal attention
  attn_kernel<<<dim3(SEQ / 64, 2 * NHEAD), 256, 0, stream>>>(qkv, o);
  // 4) x1 = x + o @ Wo^T + bo
  gemm_kernel<<<dim3(DIM / 64, T_TOK / 64), 256, 0, stream>>>(
      o, Wo, bo, x, nullptr, x1, T_TOK, DIM, DIM, GF_RESID);
  // 5) h2 = LN2(x1)   (into h)
  ln_kernel<<<T_TOK, 256, 0, stream>>>(x1, ln2_g, ln2_b, h);
  // 6) router + aux
  zero8_kernel<<<1, 32, 0, stream>>>(pifi);
  router_kernel<<<T_TOK, 128, 0, stream>>>(h, Wg, stab, pifi, pifi + 4);
  aux_kernel<<<1, 1, 0, stream>>>(pifi, pifi + 4, out);
  // 7) shared MLP: y = gelu(h2 @ Ws_up^T + bs_up) @ Ws_dn^T + bs_dn
  gemm_kernel<<<dim3(HIDD / 64, T_TOK / 64), 256, 0, stream>>>(
      h, Ws_up, bs_up, nullptr, nullptr, up, T_TOK, HIDD, DIM, GF_GELU);
  gemm_kernel<<<dim3(DIM / 64, T_TOK / 64), 256, 0, stream>>>(
      up, Ws_dn, bs_dn, nullptr, nullptr, y, T_TOK, DIM, HIDD, 0);
  // 8) MoE experts (dense): y += s_e * (gelu(h2 @ We_up^T + be_up) @ We_dn^T + be_dn)
  for (int e = 0; e < NEXP; ++e) {
    gemm_kernel<<<dim3(HIDD / 64, T_TOK / 64), 256, 0, stream>>>(
        h, We_up + (size_t)e * HIDD * DIM, be_up + (size_t)e * HIDD,
        nullptr, nullptr, up, T_TOK, HIDD, DIM, GF_GELU);
    gemm_kernel<<<dim3(DIM / 64, T_TOK / 64), 256, 0, stream>>>(
        up, We_dn + (size_t)e * DIM * HIDD, be_dn + (size_t)e * DIM,
        nullptr, stab + (size_t)e * T_TOK, y, T_TOK, DIM, HIDD, GF_SCALE | GF_ACCUM);
  }
  // 9) out = x1 + y
  add_kernel<<<(int)(TD / 256), 256, 0, stream>>>(x1, y, out + 1, (int)TD);
}

// Round 3
// 2024.461 us; speedup vs baseline: 1.3124x; 1.3124x over previous
//
#include <hip/hip_runtime.h>
#include <hip/hip_bf16.h>

// Problem constants: B=2, S=2048, D=1024, H=16, HD=64, E=4, K=2, HID=4096, T=4096
#define T_TOK 4096
#define DIM   1024
#define NHEAD 16
#define HDIM  64
#define SEQ   2048
#define NEXP  4
#define HIDD  4096

typedef short bf16x8 __attribute__((ext_vector_type(8)));
typedef float f32x4  __attribute__((ext_vector_type(4)));

enum { GF_GELU = 1, GF_RESID = 2, GF_SCALE = 4, GF_ACCUM = 8 };

__device__ inline unsigned short f2bf(float f) {
  union { float f; unsigned u; } v; v.f = f;
  unsigned r = v.u + 0x7FFFu + ((v.u >> 16) & 1u);
  return (unsigned short)(r >> 16);
}
__device__ inline float bf2f(unsigned short s) {
  union { unsigned u; float f; } v; v.u = ((unsigned)s) << 16; return v.f;
}
__device__ inline int pack2(float a, float b) {
  return (int)((unsigned)f2bf(a) | ((unsigned)f2bf(b) << 16));
}
__device__ inline float gelu_f(float x) {
  const float c = 0.7978845608028654f;
  float t = tanhf(c * (x + 0.044715f * x * x * x));
  return 0.5f * x * (1.0f + t);
}

__device__ inline void gld_lds16(const unsigned short* g, unsigned short* l) {
  __builtin_amdgcn_global_load_lds(
      (const __attribute__((address_space(1))) void*)g,
      (__attribute__((address_space(3))) void*)l, 16, 0, 0);
}

// ---------------------------------------------------------------------------
// fp32 -> bf16 cast, 8 elems/thread
// ---------------------------------------------------------------------------
__global__ __launch_bounds__(256) void cvt_kernel(
    const float* __restrict__ in, unsigned short* __restrict__ out, int n8)
{
  int i = blockIdx.x * 256 + threadIdx.x;
  if (i >= n8) return;
  const float4* p = (const float4*)in + (size_t)i * 2;
  float4 v0 = p[0], v1 = p[1];
  int4 pk = make_int4(pack2(v0.x, v0.y), pack2(v0.z, v0.w),
                      pack2(v1.x, v1.y), pack2(v1.z, v1.w));
  *(int4*)(out + (size_t)i * 8) = pk;
}

// ---------------------------------------------------------------------------
// m97-style bf16 GEMM: C = A @ W^T (+bias, epilogue). A: MxK bf16 row-major,
// W: NxK bf16 row-major. 128x128 tile, BK=32, 256 thr (4 waves, 4x4 MFMA each),
// global_load_lds width-16 staging, unpadded LDS (lane-order requirement).
// ---------------------------------------------------------------------------
__global__ __launch_bounds__(256) void gemm_bf16(
    const unsigned short* __restrict__ A, const unsigned short* __restrict__ W,
    const float* __restrict__ bias, const float* __restrict__ resid,
    const float* __restrict__ scale, float* __restrict__ C,
    unsigned short* __restrict__ C2,
    int M, int N, int Kd, int flags)
{
  __shared__ __align__(16) unsigned short As[128 * 32];
  __shared__ __align__(16) unsigned short Bs[128 * 32];

  const int tid  = threadIdx.x;
  const int wave = tid >> 6, lane = tid & 63;
  const int bm = blockIdx.y, bn = blockIdx.x;

  // staging: each wave stages 32 rows of A and 32 rows of B (2 issues of 16 rows)
  const int srow = lane >> 2;            // 0..15
  const int scol = (lane & 3) << 3;      // 0,8,16,24 (bf16 elems)
  const unsigned short* Ag = A + (size_t)(bm * 128 + wave * 32 + srow) * Kd + scol;
  const unsigned short* Wg = W + (size_t)(bn * 128 + wave * 32 + srow) * Kd + scol;
  unsigned short* AsBase = As + wave * 32 * 32;
  unsigned short* BsBase = Bs + wave * 32 * 32;

  const int wm = wave >> 1, wn = wave & 1;  // wave 2x2 grid over 128x128
  const int fr = lane & 15;                  // m (A) / n (B) / col (D)
  const int fq = lane >> 4;                  // k-quad (in) / row-quad (out)

  f32x4 acc[4][4] = {};

  for (int k0 = 0; k0 < Kd; k0 += 32) {
    __syncthreads();  // previous tile fully consumed
    gld_lds16(Ag + k0,            AsBase);
    gld_lds16(Ag + k0 + 16 * Kd,  AsBase + 16 * 32);
    gld_lds16(Wg + k0,            BsBase);
    gld_lds16(Wg + k0 + 16 * Kd,  BsBase + 16 * 32);
    __syncthreads();  // staging visible (vmcnt(0) drained by barrier)
    bf16x8 a[4], b[4];
#pragma unroll
    for (int i = 0; i < 4; ++i) {
      a[i] = *(const bf16x8*)&As[(wm * 64 + i * 16 + fr) * 32 + fq * 8];
      b[i] = *(const bf16x8*)&Bs[(wn * 64 + i * 16 + fr) * 32 + fq * 8];
    }
#pragma unroll
    for (int mt = 0; mt < 4; ++mt)
#pragma unroll
      for (int nt = 0; nt < 4; ++nt)
        acc[mt][nt] = __builtin_amdgcn_mfma_f32_16x16x32_bf16(a[mt], b[nt], acc[mt][nt], 0, 0, 0);
  }

#pragma unroll
  for (int mt = 0; mt < 4; ++mt)
#pragma unroll
    for (int nt = 0; nt < 4; ++nt)
#pragma unroll
      for (int r = 0; r < 4; ++r) {
        int row = bm * 128 + wm * 64 + mt * 16 + fq * 4 + r;
        int col = bn * 128 + wn * 64 + nt * 16 + fr;
        float v = acc[mt][nt][r] + bias[col];
        if (flags & GF_GELU) v = gelu_f(v);
        if (flags & GF_RESID) v += resid[(size_t)row * N + col];
        if (flags & GF_SCALE) v *= scale[row];
        size_t idx = (size_t)row * N + col;
        if (C) { if (flags & GF_ACCUM) C[idx] += v; else C[idx] = v; }
        if (C2) C2[idx] = f2bf(v);
      }
}

// ---------------------------------------------------------------------------
// fp32 flash attention, causal, work-balanced: block bx does Q-tiles bx and
// 31-bx (constant 33 K-tile-iters). Grid (16, B*H), 256 threads. bf16 output.
// ---------------------------------------------------------------------------
__global__ __launch_bounds__(256) void attn_kernel(
    const float* __restrict__ qkv, unsigned short* __restrict__ o)
{
  __shared__ __align__(16) float Qs[64][68];
  __shared__ __align__(16) float Ks[64][68];   // also holds P after S-compute
  __shared__ __align__(16) float Vs[64][68];

  const int tid = threadIdx.x;
  const int bh  = blockIdx.y;
  const int b   = bh >> 4, h = bh & 15;

  const int ldr = tid >> 2;             // load row 0..63
  const int ldc = (tid & 3) << 4;       // load col base (16 floats)
  const int r4 = (tid >> 4) << 2;       // thread rows r4..r4+3
  const int c4 = (tid & 15) << 2;       // thread cols c4..c4+3

  for (int half = 0; half < 2; ++half) {
    const int qb = half ? (31 - (int)blockIdx.x) : (int)blockIdx.x;
    const int q0 = qb << 6;

    const float* qp = qkv + ((size_t)(b * SEQ + q0 + ldr)) * 3072 + h * 64 + ldc;
    for (int i = 0; i < 16; i += 4)
      *(float4*)&Qs[ldr][ldc + i] = *(const float4*)(qp + i);

    float Oa[4][4] = {};
    float mr[4] = {-1e30f, -1e30f, -1e30f, -1e30f};
    float lsum[4] = {0.f, 0.f, 0.f, 0.f};

    for (int kt = 0; kt <= qb; ++kt) {
      const float* kp = qkv + ((size_t)(b * SEQ + (kt << 6) + ldr)) * 3072 + 1024 + h * 64 + ldc;
      const float* vp = kp + 1024;
      float4 kreg[4], vreg[4];
      for (int i = 0; i < 4; ++i) {
        kreg[i] = *(const float4*)(kp + i * 4);
        vreg[i] = *(const float4*)(vp + i * 4);
      }
      __syncthreads();  // prev PV reads done; Qs write drained
      for (int i = 0; i < 4; ++i) {
        *(float4*)&Ks[ldr][ldc + i * 4] = kreg[i];
        *(float4*)&Vs[ldr][ldc + i * 4] = vreg[i];
      }
      __syncthreads();  // K/V (and Qs) visible

      float s[4][4] = {};
      for (int d = 0; d < 64; d += 4) {
        float4 qv[4], kv[4];
        for (int i = 0; i < 4; ++i) qv[i] = *(const float4*)&Qs[r4 + i][d];
        for (int j = 0; j < 4; ++j) kv[j] = *(const float4*)&Ks[c4 + j][d];
        for (int i = 0; i < 4; ++i)
          for (int j = 0; j < 4; ++j)
            s[i][j] += qv[i].x * kv[j].x + qv[i].y * kv[j].y +
                       qv[i].z * kv[j].z + qv[i].w * kv[j].w;
      }
      const bool diag = (kt == qb);
      float cm[4];
      for (int i = 0; i < 4; ++i) {
        for (int j = 0; j < 4; ++j) {
          float v = s[i][j] * 0.125f;
          if (diag && (c4 + j) > (r4 + i)) v = -1e9f;
          s[i][j] = v;
        }
        cm[i] = fmaxf(fmaxf(s[i][0], s[i][1]), fmaxf(s[i][2], s[i][3]));
      }
      for (int off = 1; off < 16; off <<= 1)
        for (int i = 0; i < 4; ++i) cm[i] = fmaxf(cm[i], __shfl_xor(cm[i], off, 64));
      float al[4];
      for (int i = 0; i < 4; ++i) {
        float nm = fmaxf(mr[i], cm[i]);
        al[i] = __expf(mr[i] - nm);
        mr[i] = nm;
      }
      float ps[4];
      for (int i = 0; i < 4; ++i) {
        float a = 0.f;
        for (int j = 0; j < 4; ++j) { float p = __expf(s[i][j] - mr[i]); s[i][j] = p; a += p; }
        ps[i] = a;
      }
      for (int off = 1; off < 16; off <<= 1)
        for (int i = 0; i < 4; ++i) ps[i] += __shfl_xor(ps[i], off, 64);
      for (int i = 0; i < 4; ++i) {
        lsum[i] = lsum[i] * al[i] + ps[i];
        for (int j = 0; j < 4; ++j) Oa[i][j] *= al[i];
      }
      __syncthreads();  // all S reads of Ks done
      for (int i = 0; i < 4; ++i)
        *(float4*)&Ks[r4 + i][c4] = make_float4(s[i][0], s[i][1], s[i][2], s[i][3]);
      __syncthreads();  // P visible
      for (int k = 0; k < 64; ++k) {
        float4 vv = *(const float4*)&Vs[k][c4];
        for (int i = 0; i < 4; ++i) {
          float p = Ks[r4 + i][k];
          Oa[i][0] += p * vv.x; Oa[i][1] += p * vv.y;
          Oa[i][2] += p * vv.z; Oa[i][3] += p * vv.w;
        }
      }
    }
    unsigned short* op = o + ((size_t)(b * SEQ + q0)) * DIM + h * 64;
    for (int i = 0; i < 4; ++i) {
      float inv = 1.0f / lsum[i];
      int2 pk;
      pk.x = pack2(Oa[i][0] * inv, Oa[i][1] * inv);
      pk.y = pack2(Oa[i][2] * inv, Oa[i][3] * inv);
      *(int2*)(op + (size_t)(r4 + i) * DIM + c4) = pk;
    }
  }
}

// ---------------------------------------------------------------------------
__global__ __launch_bounds__(256) void ln_kernel(
    const float* __restrict__ x, const float* __restrict__ g,
    const float* __restrict__ b, unsigned short* __restrict__ out)
{
  const int t = blockIdx.x, tid = threadIdx.x;
  const float* row = x + (size_t)t * DIM;
  float4 v = *(const float4*)(row + tid * 4);
  float s  = v.x + v.y + v.z + v.w;
  float s2 = v.x * v.x + v.y * v.y + v.z * v.z + v.w * v.w;
  for (int off = 1; off < 64; off <<= 1) {
    s  += __shfl_xor(s, off, 64);
    s2 += __shfl_xor(s2, off, 64);
  }
  __shared__ float red[8];
  const int wave = tid >> 6, lane = tid & 63;
  if (lane == 0) { red[wave] = s; red[4 + wave] = s2; }
  __syncthreads();
  float S  = red[0] + red[1] + red[2] + red[3];
  float S2 = red[4] + red[5] + red[6] + red[7];
  float mean = S * (1.0f / DIM);
  float var  = S2 * (1.0f / DIM) - mean * mean;
  float rstd = rsqrtf(var + 1e-5f);
  float4 gv = *(const float4*)(g + tid * 4);
  float4 bv = *(const float4*)(b + tid * 4);
  float ox = (v.x - mean) * rstd * gv.x + bv.x;
  float oy = (v.y - mean) * rstd * gv.y + bv.y;
  float oz = (v.z - mean) * rstd * gv.z + bv.z;
  float ow = (v.w - mean) * rstd * gv.w + bv.w;
  int2 pk; pk.x = pack2(ox, oy); pk.y = pack2(oz, ow);
  *(int2*)(out + (size_t)t * DIM + tid * 4) = pk;
}

// ---------------------------------------------------------------------------
// Router with inline fp32 LayerNorm (matches R1 numerics: logits from fp32 h2)
// ---------------------------------------------------------------------------
__global__ __launch_bounds__(128) void router_kernel(
    const float* __restrict__ xin, const float* __restrict__ g,
    const float* __restrict__ bb, const float* __restrict__ Wgp,
    float* __restrict__ stab, float* __restrict__ pi_sum, float* __restrict__ fi_sum)
{
  const int t = blockIdx.x, tid = threadIdx.x;
  const float* row = xin + (size_t)t * DIM;
  float v[8]; float s = 0.f, s2 = 0.f;
#pragma unroll
  for (int k = 0; k < 8; ++k) {
    float u = row[tid + 128 * k];
    v[k] = u; s += u; s2 += u * u;
  }
  for (int off = 1; off < 64; off <<= 1) {
    s  += __shfl_xor(s, off, 64);
    s2 += __shfl_xor(s2, off, 64);
  }
  __shared__ float red[4];
  const int wv = tid >> 6, ln = tid & 63;
  if (ln == 0) { red[wv] = s; red[2 + wv] = s2; }
  __syncthreads();
  float S = red[0] + red[1], S2 = red[2] + red[3];
  float mean = S * (1.0f / DIM);
  float var  = S2 * (1.0f / DIM) - mean * mean;
  float rstd = rsqrtf(var + 1e-5f);
  float p0 = 0, p1 = 0, p2 = 0, p3 = 0;
#pragma unroll
  for (int k = 0; k < 8; ++k) {
    int i = tid + 128 * k;
    float hv = (v[k] - mean) * rstd * g[i] + bb[i];
    p0 += hv * Wgp[i];
    p1 += hv * Wgp[DIM + i];
    p2 += hv * Wgp[2 * DIM + i];
    p3 += hv * Wgp[3 * DIM + i];
  }
  __shared__ float sm[4][128];
  sm[0][tid] = p0; sm[1][tid] = p1; sm[2][tid] = p2; sm[3][tid] = p3;
  __syncthreads();
  for (int sft = 64; sft > 0; sft >>= 1) {
    if (tid < sft)
      for (int e = 0; e < 4; ++e) sm[e][tid] += sm[e][tid + sft];
    __syncthreads();
  }
  if (tid == 0) {
    float l[4] = { sm[0][0], sm[1][0], sm[2][0], sm[3][0] };
    float m = fmaxf(fmaxf(l[0], l[1]), fmaxf(l[2], l[3]));
    float pr[4]; float sum = 0.f;
    for (int e = 0; e < 4; ++e) { pr[e] = __expf(l[e] - m); sum += pr[e]; }
    for (int e = 0; e < 4; ++e) pr[e] /= sum;
    int i0 = 0;
    for (int e = 1; e < 4; ++e) if (pr[e] > pr[i0]) i0 = e;
    int i1 = -1;
    for (int e = 0; e < 4; ++e) if (e != i0 && (i1 < 0 || pr[e] > pr[i1])) i1 = e;
    float wsum = pr[i0] + pr[i1];
    for (int e = 0; e < 4; ++e)
      stab[(size_t)e * T_TOK + t] = (e == i0) ? pr[i0] / wsum : (e == i1) ? pr[i1] / wsum : 0.f;
    for (int e = 0; e < 4; ++e) atomicAdd(&pi_sum[e], pr[e]);
    atomicAdd(&fi_sum[i0], 1.0f);
    atomicAdd(&fi_sum[i1], 1.0f);
  }
}

__global__ void zero8_kernel(float* p) { if (threadIdx.x < 8) p[threadIdx.x] = 0.f; }

__global__ void aux_kernel(const float* __restrict__ pi_sum,
                           const float* __restrict__ fi_sum, float* __restrict__ out)
{
  float s = 0.f;
  for (int e = 0; e < 4; ++e) s += fi_sum[e] * pi_sum[e];
  out[0] = 0.01f * 4.0f * s / (2.0f * (float)T_TOK * (float)T_TOK);
}

__global__ __launch_bounds__(256) void add_kernel(
    const float* __restrict__ a, const float* __restrict__ b,
    float* __restrict__ out, int n)
{
  int i = blockIdx.x * 256 + threadIdx.x;
  if (i < n) out[i] = a[i] + b[i];
}

// ---------------------------------------------------------------------------
extern "C" void kernel_launch(void* const* d_in, const int* in_sizes, int n_in,
                              void* d_out, int out_size, void* d_ws, size_t ws_size,
                              hipStream_t stream)
{
  const float* x      = (const float*)d_in[0];
  const float* ln1_g  = (const float*)d_in[1];
  const float* ln1_b  = (const float*)d_in[2];
  const float* Wqkv   = (const float*)d_in[3];
  const float* bqkv   = (const float*)d_in[4];
  const float* Wo     = (const float*)d_in[5];
  const float* bo     = (const float*)d_in[6];
  const float* ln2_g  = (const float*)d_in[7];
  const float* ln2_b  = (const float*)d_in[8];
  const float* Wg     = (const float*)d_in[9];
  const float* We_up  = (const float*)d_in[10];
  const float* be_up  = (const float*)d_in[11];
  const float* We_dn  = (const float*)d_in[12];
  const float* be_dn  = (const float*)d_in[13];
  const float* Ws_up  = (const float*)d_in[14];
  const float* bs_up  = (const float*)d_in[15];
  const float* Ws_dn  = (const float*)d_in[16];
  const float* bs_dn  = (const float*)d_in[17];

  float* out = (float*)d_out;
  const size_t TD = (size_t)T_TOK * DIM;   // 4,194,304

  // Workspace: 104 MB total (R1's proven 112 MB was fine; R2's 136 MB may not be)
  char* w = (char*)d_ws;
  float* x1  = (float*)w;  w += TD * 4;                         // 16 MB
  float* y   = (float*)w;                                       // 16 MB
  unsigned short* o_bf = (unsigned short*)y;                    //   (o dead before y written)
  w += TD * 4;
  float* qkv = (float*)w;                                       // 48 MB
  unsigned short* up_bf = (unsigned short*)qkv;                 //   (qkv dead after attn)
  w += 3 * TD * 4;
  unsigned short* h_bf = (unsigned short*)w;  w += TD * 2;      // 8 MB
  unsigned short* P1   = (unsigned short*)w;  w += (size_t)HIDD * DIM * 2;  // 8 MB pool
  unsigned short* P2   = (unsigned short*)w;  w += (size_t)HIDD * DIM * 2;  // 8 MB pool
  float* stab = (float*)w;  w += (size_t)NEXP * T_TOK * 4;
  float* pifi = (float*)w;

  auto cvt = [&](const float* src, unsigned short* dst, int n) {
    cvt_kernel<<<(n / 8 + 255) / 256, 256, 0, stream>>>(src, dst, n / 8);
  };

  // 1) h = LN1(x) -> bf16 ; Wqkv -> P1
  cvt(Wqkv, P1, 3 * DIM * DIM);
  ln_kernel<<<T_TOK, 256, 0, stream>>>(x, ln1_g, ln1_b, h_bf);
  // 2) qkv = h @ Wqkv^T + bqkv  (fp32 out for attention)
  gemm_bf16<<<dim3(3072 / 128, T_TOK / 128), 256, 0, stream>>>(
      h_bf, P1, bqkv, nullptr, nullptr, qkv, nullptr, T_TOK, 3072, DIM, 0);
  // 3) o = causal attention -> bf16
  attn_kernel<<<dim3(16, 2 * NHEAD), 256, 0, stream>>>(qkv, o_bf);
  // 4) x1 = x + o @ Wo^T + bo
  cvt(Wo, P2, DIM * DIM);
  gemm_bf16<<<dim3(DIM / 128, T_TOK / 128), 256, 0, stream>>>(
      o_bf, P2, bo, x, nullptr, x1, nullptr, T_TOK, DIM, DIM, GF_RESID);
  // 5) h2 = LN2(x1) -> bf16 (for GEMMs)
  ln_kernel<<<T_TOK, 256, 0, stream>>>(x1, ln2_g, ln2_b, h_bf);
  // 6) router (fp32 inline LN from x1) + aux
  zero8_kernel<<<1, 32, 0, stream>>>(pifi);
  router_kernel<<<T_TOK, 128, 0, stream>>>(x1, ln2_g, ln2_b, Wg, stab, pifi, pifi + 4);
  aux_kernel<<<1, 1, 0, stream>>>(pifi, pifi + 4, out);
  // 7) shared MLP: y = gelu(h2 @ Ws_up^T + bs_up) @ Ws_dn^T + bs_dn
  cvt(Ws_up, P1, HIDD * DIM);
  gemm_bf16<<<dim3(HIDD / 128, T_TOK / 128), 256, 0, stream>>>(
      h_bf, P1, bs_up, nullptr, nullptr, nullptr, up_bf, T_TOK, HIDD, DIM, GF_GELU);
  cvt(Ws_dn, P2, DIM * HIDD);
  gemm_bf16<<<dim3(DIM / 128, T_TOK / 128), 256, 0, stream>>>(
      up_bf, P2, bs_dn, nullptr, nullptr, y, nullptr, T_TOK, DIM, HIDD, 0);
  // 8) MoE experts (dense): y += s_e * (gelu(h2 @ We_up^T + be_up) @ We_dn^T + be_dn)
  for (int e = 0; e < NEXP; ++e) {
    cvt(We_up + (size_t)e * HIDD * DIM, P1, HIDD * DIM);
    gemm_bf16<<<dim3(HIDD / 128, T_TOK / 128), 256, 0, stream>>>(
        h_bf, P1, be_up + (size_t)e * HIDD,
        nullptr, nullptr, nullptr, up_bf, T_TOK, HIDD, DIM, GF_GELU);
    cvt(We_dn + (size_t)e * DIM * HIDD, P2, DIM * HIDD);
    gemm_bf16<<<dim3(DIM / 128, T_TOK / 128), 256, 0, stream>>>(
        up_bf, P2, be_dn + (size_t)e * DIM,
        nullptr, stab + (size_t)e * T_TOK, y, nullptr, T_TOK, DIM, HIDD, GF_SCALE | GF_ACCUM);
  }
  // 9) out = x1 + y
  add_kernel<<<(int)(TD / 256), 256, 0, stream>>>(x1, y, out + 1, (int)TD);
}

// Round 5
// 1687.995 us; speedup vs baseline: 1.5740x; 1.1993x over previous
//
#include <hip/hip_runtime.h>
#include <hip/hip_bf16.h>

// Problem constants: B=2, S=2048, D=1024, H=16, HD=64, E=4, K=2, HID=4096, T=4096
#define T_TOK 4096
#define DIM   1024
#define NHEAD 16
#define HDIM  64
#define SEQ   2048
#define NEXP  4
#define HIDD  4096
#define QS    66   // attention LDS row stride (shorts)

typedef short bf16x8 __attribute__((ext_vector_type(8)));
typedef float f32x4  __attribute__((ext_vector_type(4)));

enum { GF_GELU = 1, GF_RESID = 2, GF_SCALE = 4, GF_ACCUM = 8 };

__device__ inline unsigned short f2bf(float f) {
  union { float f; unsigned u; } v; v.f = f;
  unsigned r = v.u + 0x7FFFu + ((v.u >> 16) & 1u);
  return (unsigned short)(r >> 16);
}
__device__ inline int pack2(float a, float b) {
  return (int)((unsigned)f2bf(a) | ((unsigned)f2bf(b) << 16));
}
__device__ inline float gelu_f(float x) {
  const float c = 0.7978845608028654f;
  float t = tanhf(c * (x + 0.044715f * x * x * x));
  return 0.5f * x * (1.0f + t);
}
__device__ inline void gld_lds16(const unsigned short* g, unsigned short* l) {
  __builtin_amdgcn_global_load_lds(
      (const __attribute__((address_space(1))) void*)g,
      (__attribute__((address_space(3))) void*)l, 16, 0, 0);
}

// ---------------------------------------------------------------------------
__global__ __launch_bounds__(256) void cvt_kernel(
    const float* __restrict__ in, unsigned short* __restrict__ out, int n8)
{
  int i = blockIdx.x * 256 + threadIdx.x;
  if (i >= n8) return;
  const float4* p = (const float4*)in + (size_t)i * 2;
  float4 v0 = p[0], v1 = p[1];
  int4 pk = make_int4(pack2(v0.x, v0.y), pack2(v0.z, v0.w),
                      pack2(v1.x, v1.y), pack2(v1.z, v1.w));
  *(int4*)(out + (size_t)i * 8) = pk;
}

// ---------------------------------------------------------------------------
// m97-style bf16 GEMM: C = A @ W^T (+epilogue). 128x128 tile, BK=32, 256 thr.
// Optional split-K via gridDim.z (z=0 -> C, z=1 -> Cz; both pre-initialized).
// ---------------------------------------------------------------------------
__global__ __launch_bounds__(256) void gemm_bf16(
    const unsigned short* __restrict__ A, const unsigned short* __restrict__ W,
    const float* __restrict__ bias, const float* __restrict__ resid,
    const float* __restrict__ scale, float* __restrict__ C,
    float* __restrict__ Cz, unsigned short* __restrict__ C2,
    int M, int N, int Kd, int flags)
{
  __shared__ __align__(16) unsigned short As[128 * 32];
  __shared__ __align__(16) unsigned short Bs[128 * 32];

  const int tid  = threadIdx.x;
  const int wave = tid >> 6, lane = tid & 63;
  const int bm = blockIdx.y, bn = blockIdx.x;
  const int kz = blockIdx.z;
  const int kseg = Kd / gridDim.z;       // K-range for this z-slice
  if (kz == 1) C = Cz;

  const int srow = lane >> 2;            // 0..15
  const int scol = (lane & 3) << 3;      // 0,8,16,24 (bf16 elems)
  const unsigned short* Ag = A + (size_t)(bm * 128 + wave * 32 + srow) * Kd + scol + (size_t)kz * kseg;
  const unsigned short* Wg = W + (size_t)(bn * 128 + wave * 32 + srow) * Kd + scol + (size_t)kz * kseg;
  unsigned short* AsBase = As + wave * 32 * 32;
  unsigned short* BsBase = Bs + wave * 32 * 32;

  const int wm = wave >> 1, wn = wave & 1;
  const int fr = lane & 15;
  const int fq = lane >> 4;

  f32x4 acc[4][4] = {};

  for (int k0 = 0; k0 < kseg; k0 += 32) {
    __syncthreads();
    gld_lds16(Ag + k0,            AsBase);
    gld_lds16(Ag + k0 + 16 * Kd,  AsBase + 16 * 32);
    gld_lds16(Wg + k0,            BsBase);
    gld_lds16(Wg + k0 + 16 * Kd,  BsBase + 16 * 32);
    __syncthreads();
    bf16x8 a[4], b[4];
#pragma unroll
    for (int i = 0; i < 4; ++i) {
      a[i] = *(const bf16x8*)&As[(wm * 64 + i * 16 + fr) * 32 + fq * 8];
      b[i] = *(const bf16x8*)&Bs[(wn * 64 + i * 16 + fr) * 32 + fq * 8];
    }
#pragma unroll
    for (int mt = 0; mt < 4; ++mt)
#pragma unroll
      for (int nt = 0; nt < 4; ++nt)
        acc[mt][nt] = __builtin_amdgcn_mfma_f32_16x16x32_bf16(a[mt], b[nt], acc[mt][nt], 0, 0, 0);
  }

#pragma unroll
  for (int mt = 0; mt < 4; ++mt)
#pragma unroll
    for (int nt = 0; nt < 4; ++nt)
#pragma unroll
      for (int r = 0; r < 4; ++r) {
        int row = bm * 128 + wm * 64 + mt * 16 + fq * 4 + r;
        int col = bn * 128 + wn * 64 + nt * 16 + fr;
        float v = acc[mt][nt][r];
        if (bias) v += bias[col];
        if (flags & GF_GELU) v = gelu_f(v);
        if (flags & GF_RESID) v += resid[(size_t)row * N + col];
        if (flags & GF_SCALE) v *= scale[row];
        size_t idx = (size_t)row * N + col;
        if (C) { if (flags & GF_ACCUM) C[idx] += v; else C[idx] = v; }
        if (C2) C2[idx] = f2bf(v);
      }
}

// ---------------------------------------------------------------------------
// bf16 MFMA flash attention, causal, paired Q-tiles. Grid (16, B*H), 256 thr.
// Per wave: 16 Q-rows. S via 8 QK^T MFMAs; online softmax in registers
// (quad-shuffles); P roundtrip via wave-private LDS; PV via 8 MFMAs with V^T.
// ---------------------------------------------------------------------------
__global__ __launch_bounds__(256) void attn_mfma(
    const unsigned short* __restrict__ qkv, unsigned short* __restrict__ o)
{
  __shared__ __align__(16) unsigned short Qs[64 * QS];
  __shared__ __align__(16) unsigned short Ks[64 * QS];
  __shared__ __align__(16) unsigned short Vt[64 * QS];  // transposed: Vt[d][k]
  __shared__ __align__(16) unsigned short Ps[64 * QS];  // wave-private 16-row bands

  const int tid  = threadIdx.x;
  const int wave = tid >> 6, lane = tid & 63;
  const int quad = lane >> 4, l15 = lane & 15;
  const int bh = blockIdx.y, b = bh >> 4, h = bh & 15;

  const int srow = tid >> 2;            // staging row 0..63
  const int scol = (tid & 3) << 4;      // staging col base (16 shorts)

  for (int half = 0; half < 2; ++half) {
    const int qb = half ? (31 - (int)blockIdx.x) : (int)blockIdx.x;
    const int q0 = qb << 6;

    __syncthreads();  // prior half fully done before overwriting Qs
    {
      const unsigned short* qp = qkv + ((size_t)(b * SEQ + q0 + srow)) * 3072 + h * 64 + scol;
      *(int4*)&Qs[srow * QS + scol]     = *(const int4*)qp;
      *(int4*)&Qs[srow * QS + scol + 8] = *(const int4*)(qp + 8);
    }
    __syncthreads();
    bf16x8 qf0 = *(const bf16x8*)&Qs[(wave * 16 + l15) * QS + quad * 8];
    bf16x8 qf1 = *(const bf16x8*)&Qs[(wave * 16 + l15) * QS + 32 + quad * 8];

    f32x4 Oc[4] = {};
    float mr[4] = {-1e30f, -1e30f, -1e30f, -1e30f};
    float ls[4] = {0.f, 0.f, 0.f, 0.f};

    for (int kt = 0; kt <= qb; ++kt) {
      __syncthreads();  // previous iteration's K/Vt reads complete
      {
        const unsigned short* kp = qkv + ((size_t)(b * SEQ + (kt << 6) + srow)) * 3072 + 1024 + h * 64 + scol;
        const unsigned short* vp = kp + 1024;
        *(int4*)&Ks[srow * QS + scol]     = *(const int4*)kp;
        *(int4*)&Ks[srow * QS + scol + 8] = *(const int4*)(kp + 8);
        unsigned short vs[16];
        *(int4*)&vs[0] = *(const int4*)vp;
        *(int4*)&vs[8] = *(const int4*)(vp + 8);
#pragma unroll
        for (int i = 0; i < 16; ++i)
          Vt[(scol + i) * QS + srow] = vs[i];
      }
      __syncthreads();

      // S = Q K^T  (per wave: 16 rows x 64 cols = 4 col-tiles)
      f32x4 sc[4] = {};
#pragma unroll
      for (int ct = 0; ct < 4; ++ct) {
        bf16x8 k0 = *(const bf16x8*)&Ks[(ct * 16 + l15) * QS + quad * 8];
        bf16x8 k1 = *(const bf16x8*)&Ks[(ct * 16 + l15) * QS + 32 + quad * 8];
        sc[ct] = __builtin_amdgcn_mfma_f32_16x16x32_bf16(qf0, k0, sc[ct], 0, 0, 0);
        sc[ct] = __builtin_amdgcn_mfma_f32_16x16x32_bf16(qf1, k1, sc[ct], 0, 0, 0);
      }

      // scale + causal mask (C-layout: local col = ct*16+l15,
      // local row within tile = wave*16 + quad*4 + r  — wave offset REQUIRED)
      float sv[4][4];
      const bool diag = (kt == qb);
#pragma unroll
      for (int ct = 0; ct < 4; ++ct)
#pragma unroll
        for (int r = 0; r < 4; ++r) {
          float v = sc[ct][r] * 0.125f;
          if (diag && (ct * 16 + l15) > (wave * 16 + quad * 4 + r)) v = -1e9f;
          sv[ct][r] = v;
        }
      // row stats (rows live in one 16-lane group)
      float rm[4], rs[4];
#pragma unroll
      for (int r = 0; r < 4; ++r)
        rm[r] = fmaxf(fmaxf(sv[0][r], sv[1][r]), fmaxf(sv[2][r], sv[3][r]));
#pragma unroll
      for (int m = 1; m < 16; m <<= 1)
#pragma unroll
        for (int r = 0; r < 4; ++r) rm[r] = fmaxf(rm[r], __shfl_xor(rm[r], m, 16));
      float al[4];
#pragma unroll
      for (int r = 0; r < 4; ++r) {
        float nm = fmaxf(mr[r], rm[r]);
        al[r] = __expf(mr[r] - nm);
        mr[r] = nm;
        rs[r] = 0.f;
      }
#pragma unroll
      for (int ct = 0; ct < 4; ++ct)
#pragma unroll
        for (int r = 0; r < 4; ++r) {
          float p = __expf(sv[ct][r] - mr[r]);
          sv[ct][r] = p;
          rs[r] += p;
        }
#pragma unroll
      for (int m = 1; m < 16; m <<= 1)
#pragma unroll
        for (int r = 0; r < 4; ++r) rs[r] += __shfl_xor(rs[r], m, 16);
#pragma unroll
      for (int r = 0; r < 4; ++r) {
        ls[r] = ls[r] * al[r] + rs[r];
        for (int ct = 0; ct < 4; ++ct) Oc[ct][r] *= al[r];
      }
      // P -> LDS (wave-private band, no barrier needed)
#pragma unroll
      for (int ct = 0; ct < 4; ++ct)
#pragma unroll
        for (int r = 0; r < 4; ++r)
          Ps[(wave * 16 + quad * 4 + r) * QS + ct * 16 + l15] = f2bf(sv[ct][r]);
      // PV
      bf16x8 pf0 = *(const bf16x8*)&Ps[(wave * 16 + l15) * QS + quad * 8];
      bf16x8 pf1 = *(const bf16x8*)&Ps[(wave * 16 + l15) * QS + 32 + quad * 8];
#pragma unroll
      for (int ct = 0; ct < 4; ++ct) {
        bf16x8 v0 = *(const bf16x8*)&Vt[(ct * 16 + l15) * QS + quad * 8];
        bf16x8 v1 = *(const bf16x8*)&Vt[(ct * 16 + l15) * QS + 32 + quad * 8];
        Oc[ct] = __builtin_amdgcn_mfma_f32_16x16x32_bf16(pf0, v0, Oc[ct], 0, 0, 0);
        Oc[ct] = __builtin_amdgcn_mfma_f32_16x16x32_bf16(pf1, v1, Oc[ct], 0, 0, 0);
      }
    }

#pragma unroll
    for (int r = 0; r < 4; ++r) {
      float inv = 1.0f / ls[r];
      unsigned short* orow = o + ((size_t)(b * SEQ + q0 + wave * 16 + quad * 4 + r)) * DIM + h * 64;
#pragma unroll
      for (int ct = 0; ct < 4; ++ct)
        orow[ct * 16 + l15] = f2bf(Oc[ct][r] * inv);
    }
  }
}

// ---------------------------------------------------------------------------
__global__ __launch_bounds__(256) void ln_kernel(
    const float* __restrict__ x, const float* __restrict__ g,
    const float* __restrict__ b, unsigned short* __restrict__ out)
{
  const int t = blockIdx.x, tid = threadIdx.x;
  const float* row = x + (size_t)t * DIM;
  float4 v = *(const float4*)(row + tid * 4);
  float s  = v.x + v.y + v.z + v.w;
  float s2 = v.x * v.x + v.y * v.y + v.z * v.z + v.w * v.w;
  for (int off = 1; off < 64; off <<= 1) {
    s  += __shfl_xor(s, off, 64);
    s2 += __shfl_xor(s2, off, 64);
  }
  __shared__ float red[8];
  const int wave = tid >> 6, lane = tid & 63;
  if (lane == 0) { red[wave] = s; red[4 + wave] = s2; }
  __syncthreads();
  float S  = red[0] + red[1] + red[2] + red[3];
  float S2 = red[4] + red[5] + red[6] + red[7];
  float mean = S * (1.0f / DIM);
  float var  = S2 * (1.0f / DIM) - mean * mean;
  float rstd = rsqrtf(var + 1e-5f);
  float4 gv = *(const float4*)(g + tid * 4);
  float4 bv = *(const float4*)(b + tid * 4);
  float ox = (v.x - mean) * rstd * gv.x + bv.x;
  float oy = (v.y - mean) * rstd * gv.y + bv.y;
  float oz = (v.z - mean) * rstd * gv.z + bv.z;
  float ow = (v.w - mean) * rstd * gv.w + bv.w;
  int2 pk; pk.x = pack2(ox, oy); pk.y = pack2(oz, ow);
  *(int2*)(out + (size_t)t * DIM + tid * 4) = pk;
}

// ---------------------------------------------------------------------------
__global__ __launch_bounds__(128) void router_kernel(
    const float* __restrict__ xin, const float* __restrict__ g,
    const float* __restrict__ bb, const float* __restrict__ Wgp,
    float* __restrict__ stab, float* __restrict__ pi_sum, float* __restrict__ fi_sum)
{
  const int t = blockIdx.x, tid = threadIdx.x;
  const float* row = xin + (size_t)t * DIM;
  float v[8]; float s = 0.f, s2 = 0.f;
#pragma unroll
  for (int k = 0; k < 8; ++k) {
    float u = row[tid + 128 * k];
    v[k] = u; s += u; s2 += u * u;
  }
  for (int off = 1; off < 64; off <<= 1) {
    s  += __shfl_xor(s, off, 64);
    s2 += __shfl_xor(s2, off, 64);
  }
  __shared__ float red[4];
  const int wv = tid >> 6, ln = tid & 63;
  if (ln == 0) { red[wv] = s; red[2 + wv] = s2; }
  __syncthreads();
  float S = red[0] + red[1], S2 = red[2] + red[3];
  float mean = S * (1.0f / DIM);
  float var  = S2 * (1.0f / DIM) - mean * mean;
  float rstd = rsqrtf(var + 1e-5f);
  float p0 = 0, p1 = 0, p2 = 0, p3 = 0;
#pragma unroll
  for (int k = 0; k < 8; ++k) {
    int i = tid + 128 * k;
    float hv = (v[k] - mean) * rstd * g[i] + bb[i];
    p0 += hv * Wgp[i];
    p1 += hv * Wgp[DIM + i];
    p2 += hv * Wgp[2 * DIM + i];
    p3 += hv * Wgp[3 * DIM + i];
  }
  __shared__ float sm[4][128];
  sm[0][tid] = p0; sm[1][tid] = p1; sm[2][tid] = p2; sm[3][tid] = p3;
  __syncthreads();
  for (int sft = 64; sft > 0; sft >>= 1) {
    if (tid < sft)
      for (int e = 0; e < 4; ++e) sm[e][tid] += sm[e][tid + sft];
    __syncthreads();
  }
  if (tid == 0) {
    float l[4] = { sm[0][0], sm[1][0], sm[2][0], sm[3][0] };
    float m = fmaxf(fmaxf(l[0], l[1]), fmaxf(l[2], l[3]));
    float pr[4]; float sum = 0.f;
    for (int e = 0; e < 4; ++e) { pr[e] = __expf(l[e] - m); sum += pr[e]; }
    for (int e = 0; e < 4; ++e) pr[e] /= sum;
    int i0 = 0;
    for (int e = 1; e < 4; ++e) if (pr[e] > pr[i0]) i0 = e;
    int i1 = -1;
    for (int e = 0; e < 4; ++e) if (e != i0 && (i1 < 0 || pr[e] > pr[i1])) i1 = e;
    float wsum = pr[i0] + pr[i1];
    for (int e = 0; e < 4; ++e)
      stab[(size_t)e * T_TOK + t] = (e == i0) ? pr[i0] / wsum : (e == i1) ? pr[i1] / wsum : 0.f;
    for (int e = 0; e < 4; ++e) atomicAdd(&pi_sum[e], pr[e]);
    atomicAdd(&fi_sum[i0], 1.0f);
    atomicAdd(&fi_sum[i1], 1.0f);
  }
}

__global__ void zero8_kernel(float* p) { if (threadIdx.x < 8) p[threadIdx.x] = 0.f; }

__global__ void aux_kernel(const float* __restrict__ pi_sum,
                           const float* __restrict__ fi_sum, float* __restrict__ out)
{
  float s = 0.f;
  for (int e = 0; e < 4; ++e) s += fi_sum[e] * pi_sum[e];
  out[0] = 0.01f * 4.0f * s / (2.0f * (float)T_TOK * (float)T_TOK);
}

// y = bs_dn + sum_e stab[e]*be_dn[e]; y2 = 0
__global__ __launch_bounds__(256) void init_y_kernel(
    const float* __restrict__ bs_dn, const float* __restrict__ be_dn,
    const float* __restrict__ stab, float* __restrict__ y, float* __restrict__ y2)
{
  const int t = blockIdx.x, c = threadIdx.x;
  float s0 = stab[t], s1 = stab[T_TOK + t], s2 = stab[2 * T_TOK + t], s3 = stab[3 * T_TOK + t];
  float4 acc = ((const float4*)bs_dn)[c];
  float4 b0 = ((const float4*)(be_dn + 0 * DIM))[c];
  float4 b1 = ((const float4*)(be_dn + 1 * DIM))[c];
  float4 b2 = ((const float4*)(be_dn + 2 * DIM))[c];
  float4 b3 = ((const float4*)(be_dn + 3 * DIM))[c];
  acc.x += s0 * b0.x + s1 * b1.x + s2 * b2.x + s3 * b3.x;
  acc.y += s0 * b0.y + s1 * b1.y + s2 * b2.y + s3 * b3.y;
  acc.z += s0 * b0.z + s1 * b1.z + s2 * b2.z + s3 * b3.z;
  acc.w += s0 * b0.w + s1 * b1.w + s2 * b2.w + s3 * b3.w;
  ((float4*)(y + (size_t)t * DIM))[c] = acc;
  ((float4*)(y2 + (size_t)t * DIM))[c] = make_float4(0.f, 0.f, 0.f, 0.f);
}

__global__ __launch_bounds__(256) void add3_kernel(
    const float* __restrict__ a, const float* __restrict__ b,
    const float* __restrict__ c, float* __restrict__ out, int n)
{
  int i = blockIdx.x * 256 + threadIdx.x;
  if (i < n) out[i] = a[i] + b[i] + c[i];
}

// ---------------------------------------------------------------------------
extern "C" void kernel_launch(void* const* d_in, const int* in_sizes, int n_in,
                              void* d_out, int out_size, void* d_ws, size_t ws_size,
                              hipStream_t stream)
{
  const float* x      = (const float*)d_in[0];
  const float* ln1_g  = (const float*)d_in[1];
  const float* ln1_b  = (const float*)d_in[2];
  const float* Wqkv   = (const float*)d_in[3];
  const float* bqkv   = (const float*)d_in[4];
  const float* Wo     = (const float*)d_in[5];
  const float* bo     = (const float*)d_in[6];
  const float* ln2_g  = (const float*)d_in[7];
  const float* ln2_b  = (const float*)d_in[8];
  const float* Wg     = (const float*)d_in[9];
  const float* We_up  = (const float*)d_in[10];
  const float* be_up  = (const float*)d_in[11];
  const float* We_dn  = (const float*)d_in[12];
  const float* be_dn  = (const float*)d_in[13];
  const float* Ws_up  = (const float*)d_in[14];
  const float* bs_up  = (const float*)d_in[15];
  const float* Ws_dn  = (const float*)d_in[16];
  const float* bs_dn  = (const float*)d_in[17];

  float* out = (float*)d_out;
  const size_t TD = (size_t)T_TOK * DIM;   // 4,194,304

  // Workspace: ~104 MB
  char* w = (char*)d_ws;
  float* x1 = (float*)w;  w += TD * 4;                          // 16 MB
  float* y  = (float*)w;                                        // 16 MB
  unsigned short* o_bf = (unsigned short*)y;                    //   (o dead before init_y)
  w += TD * 4;
  float* y2 = (float*)w;  w += TD * 4;                          // 16 MB
  unsigned short* pool = (unsigned short*)w;                    // 32 MB: qkv_bf then up_bf
  unsigned short* qkv_bf = pool;
  unsigned short* up_bf  = pool;
  w += (size_t)T_TOK * HIDD * 2;
  unsigned short* h_bf = (unsigned short*)w;  w += TD * 2;      // 8 MB
  unsigned short* P1   = (unsigned short*)w;  w += (size_t)HIDD * DIM * 2;  // 8 MB
  unsigned short* P2   = (unsigned short*)w;  w += (size_t)HIDD * DIM * 2;  // 8 MB
  float* stab = (float*)w;  w += (size_t)NEXP * T_TOK * 4;
  float* pifi = (float*)w;

  auto cvt = [&](const float* src, unsigned short* dst, int n) {
    cvt_kernel<<<(n / 8 + 255) / 256, 256, 0, stream>>>(src, dst, n / 8);
  };

  // 1) h = LN1(x) -> bf16 ; Wqkv -> P1
  cvt(Wqkv, P1, 3 * DIM * DIM);
  ln_kernel<<<T_TOK, 256, 0, stream>>>(x, ln1_g, ln1_b, h_bf);
  // 2) qkv (bf16 only)
  gemm_bf16<<<dim3(3072 / 128, T_TOK / 128), 256, 0, stream>>>(
      h_bf, P1, bqkv, nullptr, nullptr, nullptr, nullptr, qkv_bf, T_TOK, 3072, DIM, 0);
  // 3) o = causal MFMA attention -> bf16
  attn_mfma<<<dim3(16, 2 * NHEAD), 256, 0, stream>>>(qkv_bf, o_bf);
  // 4) x1 = x + o @ Wo^T + bo
  cvt(Wo, P2, DIM * DIM);
  gemm_bf16<<<dim3(DIM / 128, T_TOK / 128), 256, 0, stream>>>(
      o_bf, P2, bo, x, nullptr, x1, nullptr, nullptr, T_TOK, DIM, DIM, GF_RESID);
  // 5) h2 = LN2(x1) -> bf16
  ln_kernel<<<T_TOK, 256, 0, stream>>>(x1, ln2_g, ln2_b, h_bf);
  // 6) router (fp32 inline LN from x1) + aux
  zero8_kernel<<<1, 32, 0, stream>>>(pifi);
  router_kernel<<<T_TOK, 128, 0, stream>>>(x1, ln2_g, ln2_b, Wg, stab, pifi, pifi + 4);
  aux_kernel<<<1, 1, 0, stream>>>(pifi, pifi + 4, out);
  // 7) y/y2 init with all down-proj biases folded in
  init_y_kernel<<<T_TOK, 256, 0, stream>>>(bs_dn, be_dn, stab, y, y2);
  // 8) shared MLP: up (gelu) then split-K down accumulate
  cvt(Ws_up, P1, HIDD * DIM);
  gemm_bf16<<<dim3(HIDD / 128, T_TOK / 128), 256, 0, stream>>>(
      h_bf, P1, bs_up, nullptr, nullptr, nullptr, nullptr, up_bf, T_TOK, HIDD, DIM, GF_GELU);
  cvt(Ws_dn, P2, DIM * HIDD);
  gemm_bf16<<<dim3(DIM / 128, T_TOK / 128, 2), 256, 0, stream>>>(
      up_bf, P2, nullptr, nullptr, nullptr, y, y2, nullptr, T_TOK, DIM, HIDD, GF_ACCUM);
  // 9) MoE experts: scale folded into up epilogue; down pure accumulate
  for (int e = 0; e < NEXP; ++e) {
    cvt(We_up + (size_t)e * HIDD * DIM, P1, HIDD * DIM);
    gemm_bf16<<<dim3(HIDD / 128, T_TOK / 128), 256, 0, stream>>>(
        h_bf, P1, be_up + (size_t)e * HIDD,
        nullptr, stab + (size_t)e * T_TOK, nullptr, nullptr, up_bf,
        T_TOK, HIDD, DIM, GF_GELU | GF_SCALE);
    cvt(We_dn + (size_t)e * DIM * HIDD, P2, DIM * HIDD);
    gemm_bf16<<<dim3(DIM / 128, T_TOK / 128, 2), 256, 0, stream>>>(
        up_bf, P2, nullptr, nullptr, nullptr, y, y2, nullptr,
        T_TOK, DIM, HIDD, GF_ACCUM);
  }
  // 10) out = x1 + y + y2
  add3_kernel<<<(int)(TD / 256), 256, 0, stream>>>(x1, y, y2, out + 1, (int)TD);
}